// Round 1
// baseline (1124.099 us; speedup 1.0000x reference)
//
#include <hip/hip_runtime.h>
#include <math.h>

#define BATCH 8
#define DD    512
#define NNPIX 4096
#define RR    64
#define NSTEPS 7
#define INV_T 100.0f
#define EPSV  1e-6f

// ---------------------------------------------------------------------------
// partial gram: pg[b][chunk][r][s] = sum_{d in chunk of 64 rows} M[d][r]*M[d][s]
__global__ __launch_bounds__(256) void pgram_kernel(
    const float* __restrict__ mat, float* __restrict__ pg, int rows_total) {
  __shared__ float t[64 * 65];
  const int b = blockIdx.y, c = blockIdx.x;
  const float* mp = mat + ((size_t)b * rows_total + (size_t)c * 64) * RR;
  const int tid = threadIdx.x;
  for (int i = tid; i < 64 * 16; i += 256) {
    const int row = i >> 4, c4 = (i & 15) * 4;
    const float4 v = *(const float4*)(mp + row * RR + c4);
    t[row * 65 + c4 + 0] = v.x;
    t[row * 65 + c4 + 1] = v.y;
    t[row * 65 + c4 + 2] = v.z;
    t[row * 65 + c4 + 3] = v.w;
  }
  __syncthreads();
  const int tx = tid & 15, ty = tid >> 4;
  float acc[4][4] = {};
  for (int d = 0; d < 64; ++d) {
    float a[4], bb[4];
#pragma unroll
    for (int i = 0; i < 4; ++i) a[i] = t[d * 65 + ty * 4 + i];
#pragma unroll
    for (int j = 0; j < 4; ++j) bb[j] = t[d * 65 + tx * 4 + j];
#pragma unroll
    for (int i = 0; i < 4; ++i)
#pragma unroll
      for (int j = 0; j < 4; ++j) acc[i][j] = fmaf(a[i], bb[j], acc[i][j]);
  }
  float* op = pg + ((size_t)b * gridDim.x + c) * 4096;
#pragma unroll
  for (int i = 0; i < 4; ++i) {
    float4 v = make_float4(acc[i][0], acc[i][1], acc[i][2], acc[i][3]);
    *(float4*)(op + (ty * 4 + i) * 64 + tx * 4) = v;
  }
}

// g[b][e] = sum_{c<nchunks} pg[b][c][e],  e in [0,4096)
__global__ __launch_bounds__(256) void greduce_kernel(
    const float* __restrict__ pg, float* __restrict__ g, int nchunks) {
  const int idx = blockIdx.x * 256 + threadIdx.x;  // 0..32767
  const int b = idx >> 12, e = idx & 4095;
  const float* p = pg + (size_t)b * nchunks * 4096 + e;
  float s = 0.f;
  for (int c = 0; c < nchunks; ++c) s += p[(size_t)c * 4096];
  g[idx] = s;
}

// ---------------------------------------------------------------------------
// coef kernel: computes num = x^T @ bases for a 64-row n-tile (full R=64),
// then MODE 0: coef = softmax(INV_T*num)
//      MODE 1: coef *= num/(coef@gram_b+eps), emit partial coef^T coef
//      MODE 2: MODE 1 without the partial gram
template <int MODE>
__global__ __launch_bounds__(256) void coef_kernel(
    const float* __restrict__ x, const float* __restrict__ bases,
    const float* __restrict__ gram_b, float* __restrict__ coef,
    float* __restrict__ pgc) {
  __shared__ float smem[64 * 65 + 64 * 64];
  float* xs = smem;          // [32][64] during GEMM
  float* bs = smem + 2048;   // [32][64] during GEMM
  const int b = blockIdx.y, nt = blockIdx.x;
  const int n0 = nt * 64;
  const float* xp = x + (size_t)b * DD * NNPIX + n0;
  const float* bp = bases + (size_t)b * DD * RR;
  const int tid = threadIdx.x, tx = tid & 15, ty = tid >> 4;

  float acc[4][4] = {};
  for (int k0 = 0; k0 < DD; k0 += 32) {
#pragma unroll
    for (int i = 0; i < 2; ++i) {
      const int idx = tid + i * 256;  // 0..511 float4 slots
      const int row = idx >> 4, c4 = (idx & 15) * 4;
      *(float4*)&xs[row * 64 + c4] =
          *(const float4*)(xp + (size_t)(k0 + row) * NNPIX + c4);
      *(float4*)&bs[row * 64 + c4] =
          *(const float4*)(bp + (size_t)(k0 + row) * RR + c4);
    }
    __syncthreads();
#pragma unroll
    for (int k = 0; k < 32; ++k) {
      const float4 av = *(float4*)&xs[k * 64 + ty * 4];
      const float4 bv = *(float4*)&bs[k * 64 + tx * 4];
      const float a[4] = {av.x, av.y, av.z, av.w};
      const float bb[4] = {bv.x, bv.y, bv.z, bv.w};
#pragma unroll
      for (int i = 0; i < 4; ++i)
#pragma unroll
        for (int j = 0; j < 4; ++j) acc[i][j] = fmaf(a[i], bb[j], acc[i][j]);
    }
    __syncthreads();
  }

  float* cs = smem;            // [64][65]
  float* gs = smem + 64 * 65;  // [64][64]
  float* cg = coef + (size_t)b * NNPIX * RR + (size_t)n0 * RR;

  if (MODE == 0) {
#pragma unroll
    for (int i = 0; i < 4; ++i)
#pragma unroll
      for (int j = 0; j < 4; ++j)
        cs[(ty * 4 + i) * 65 + tx * 4 + j] = acc[i][j];
    __syncthreads();
    if (tid < 64) {
      float* row = cs + tid * 65;
      float m = -1e30f;
      for (int r = 0; r < 64; ++r) m = fmaxf(m, row[r]);
      float s = 0.f;
      for (int r = 0; r < 64; ++r) {
        const float e = expf(INV_T * (row[r] - m));
        row[r] = e;
        s += e;
      }
      const float inv = 1.f / s;
      for (int r = 0; r < 64; ++r) row[r] *= inv;
    }
    __syncthreads();
    for (int idx = tid; idx < 4096; idx += 256) {
      const int row = idx >> 6, cc = idx & 63;
      cg[row * 64 + cc] = cs[row * 65 + cc];
    }
    return;
  }

  // MODE 1 / 2: load current coef tile + gram_b
  for (int idx = tid; idx < 4096; idx += 256) {
    const int row = idx >> 6, cc = idx & 63;
    cs[row * 65 + cc] = cg[row * 64 + cc];
  }
  {
    const float* gbp = gram_b + (size_t)b * 4096;
    for (int idx = tid; idx < 1024; idx += 256)
      *(float4*)&gs[idx * 4] = *(const float4*)(gbp + idx * 4);
  }
  __syncthreads();

  float den[4][4] = {};
  for (int s = 0; s < 64; ++s) {
    float a[4];
#pragma unroll
    for (int i = 0; i < 4; ++i) a[i] = cs[(ty * 4 + i) * 65 + s];
    const float4 gv = *(float4*)&gs[s * 64 + tx * 4];
    const float g4[4] = {gv.x, gv.y, gv.z, gv.w};
#pragma unroll
    for (int i = 0; i < 4; ++i)
#pragma unroll
      for (int j = 0; j < 4; ++j) den[i][j] = fmaf(a[i], g4[j], den[i][j]);
  }
  __syncthreads();  // all dens computed before cs is overwritten

#pragma unroll
  for (int i = 0; i < 4; ++i) {
    float4 vv;
    float* vp = &vv.x;
#pragma unroll
    for (int j = 0; j < 4; ++j) {
      const float oldc = cs[(ty * 4 + i) * 65 + tx * 4 + j];
      const float v = oldc * acc[i][j] / (den[i][j] + EPSV);
      vp[j] = v;
      cs[(ty * 4 + i) * 65 + tx * 4 + j] = v;
    }
    *(float4*)&cg[(ty * 4 + i) * 64 + tx * 4] = vv;
  }
  if (MODE == 1) {
    __syncthreads();  // new coef tile visible to all
    float pa[4][4] = {};
    for (int n = 0; n < 64; ++n) {
      float a[4], bb[4];
#pragma unroll
      for (int i = 0; i < 4; ++i) a[i] = cs[n * 65 + ty * 4 + i];
#pragma unroll
      for (int j = 0; j < 4; ++j) bb[j] = cs[n * 65 + tx * 4 + j];
#pragma unroll
      for (int i = 0; i < 4; ++i)
#pragma unroll
        for (int j = 0; j < 4; ++j) pa[i][j] = fmaf(a[i], bb[j], pa[i][j]);
    }
    float* pp = pgc + ((size_t)b * 64 + nt) * 4096;
#pragma unroll
    for (int i = 0; i < 4; ++i) {
      float4 v = make_float4(pa[i][0], pa[i][1], pa[i][2], pa[i][3]);
      *(float4*)(pp + (ty * 4 + i) * 64 + tx * 4) = v;
    }
  }
}

// ---------------------------------------------------------------------------
// partial num_b: pnb[b][kc][d][r] = sum_{n in kc-chunk of 1024} x[d][n]*coef[n][r]
__global__ __launch_bounds__(256) void numb_partial_kernel(
    const float* __restrict__ x, const float* __restrict__ coef,
    float* __restrict__ pnb) {
  __shared__ float xs[64 * 36];   // [d][k] padded
  __shared__ float cs2[32 * 64];  // [k][r]
  const int kc = blockIdx.x, dt = blockIdx.y, b = blockIdx.z;
  const float* xp = x + (size_t)b * DD * NNPIX + (size_t)(dt * 64) * NNPIX + kc * 1024;
  const float* cp = coef + (size_t)b * NNPIX * RR + (size_t)(kc * 1024) * RR;
  const int tid = threadIdx.x, tx = tid & 15, ty = tid >> 4;
  float acc[4][4] = {};
  for (int k0 = 0; k0 < 1024; k0 += 32) {
#pragma unroll
    for (int i = 0; i < 2; ++i) {
      const int idx = tid + i * 256;  // 0..511
      {
        const int row = idx >> 3, c4 = (idx & 7) * 4;  // x: 64 rows x 32 cols
        const float4 v = *(const float4*)(xp + (size_t)row * NNPIX + k0 + c4);
        xs[row * 36 + c4 + 0] = v.x;
        xs[row * 36 + c4 + 1] = v.y;
        xs[row * 36 + c4 + 2] = v.z;
        xs[row * 36 + c4 + 3] = v.w;
      }
      {
        const int row = idx >> 4, c4 = (idx & 15) * 4;  // coef: 32 rows x 64 cols
        *(float4*)&cs2[row * 64 + c4] =
            *(const float4*)(cp + (size_t)(k0 + row) * RR + c4);
      }
    }
    __syncthreads();
#pragma unroll
    for (int k = 0; k < 32; ++k) {
      float a[4];
#pragma unroll
      for (int i = 0; i < 4; ++i) a[i] = xs[(ty * 4 + i) * 36 + k];
      const float4 cv = *(float4*)&cs2[k * 64 + tx * 4];
      const float bb[4] = {cv.x, cv.y, cv.z, cv.w};
#pragma unroll
      for (int i = 0; i < 4; ++i)
#pragma unroll
        for (int j = 0; j < 4; ++j) acc[i][j] = fmaf(a[i], bb[j], acc[i][j]);
    }
    __syncthreads();
  }
  float* pp = pnb + (((size_t)b * 4 + kc) * DD + dt * 64) * RR;
#pragma unroll
  for (int i = 0; i < 4; ++i) {
    float4 v = make_float4(acc[i][0], acc[i][1], acc[i][2], acc[i][3]);
    *(float4*)(pp + (ty * 4 + i) * RR + tx * 4) = v;
  }
}

// ---------------------------------------------------------------------------
// bases update: B *= num_b/(B@gram_c+eps); emit partial B^T B per d-tile
__global__ __launch_bounds__(256) void bases_update_kernel(
    const float* __restrict__ pnb, const float* __restrict__ gram_c,
    float* __restrict__ bases, float* __restrict__ pgb) {
  __shared__ float bsm[64 * 65];
  __shared__ float gs[64 * 64];
  const int dt = blockIdx.x, b = blockIdx.y;
  float* bg = bases + (size_t)b * DD * RR + (size_t)(dt * 64) * RR;
  const int tid = threadIdx.x, tx = tid & 15, ty = tid >> 4;
  for (int idx = tid; idx < 4096; idx += 256) {
    const int row = idx >> 6, cc = idx & 63;
    bsm[row * 65 + cc] = bg[row * 64 + cc];
  }
  {
    const float* gcp = gram_c + (size_t)b * 4096;
    for (int idx = tid; idx < 1024; idx += 256)
      *(float4*)&gs[idx * 4] = *(const float4*)(gcp + idx * 4);
  }
  __syncthreads();

  float nb[4][4];
#pragma unroll
  for (int i = 0; i < 4; ++i) {
    float4 s = make_float4(0.f, 0.f, 0.f, 0.f);
#pragma unroll
    for (int kc = 0; kc < 4; ++kc) {
      const float4 v = *(const float4*)(pnb +
          (((size_t)b * 4 + kc) * DD + dt * 64 + ty * 4 + i) * RR + tx * 4);
      s.x += v.x; s.y += v.y; s.z += v.z; s.w += v.w;
    }
    nb[i][0] = s.x; nb[i][1] = s.y; nb[i][2] = s.z; nb[i][3] = s.w;
  }

  float den[4][4] = {};
  for (int s = 0; s < 64; ++s) {
    float a[4];
#pragma unroll
    for (int i = 0; i < 4; ++i) a[i] = bsm[(ty * 4 + i) * 65 + s];
    const float4 gv = *(float4*)&gs[s * 64 + tx * 4];
    const float g4[4] = {gv.x, gv.y, gv.z, gv.w};
#pragma unroll
    for (int i = 0; i < 4; ++i)
#pragma unroll
      for (int j = 0; j < 4; ++j) den[i][j] = fmaf(a[i], g4[j], den[i][j]);
  }
  __syncthreads();

#pragma unroll
  for (int i = 0; i < 4; ++i) {
    float4 vv;
    float* vp = &vv.x;
#pragma unroll
    for (int j = 0; j < 4; ++j) {
      const float oldb = bsm[(ty * 4 + i) * 65 + tx * 4 + j];
      const float v = oldb * nb[i][j] / (den[i][j] + EPSV);
      vp[j] = v;
      bsm[(ty * 4 + i) * 65 + tx * 4 + j] = v;
    }
    *(float4*)&bg[(ty * 4 + i) * 64 + tx * 4] = vv;
  }
  __syncthreads();

  float pa[4][4] = {};
  for (int d = 0; d < 64; ++d) {
    float a[4], bb[4];
#pragma unroll
    for (int i = 0; i < 4; ++i) a[i] = bsm[d * 65 + ty * 4 + i];
#pragma unroll
    for (int j = 0; j < 4; ++j) bb[j] = bsm[d * 65 + tx * 4 + j];
#pragma unroll
    for (int i = 0; i < 4; ++i)
#pragma unroll
      for (int j = 0; j < 4; ++j) pa[i][j] = fmaf(a[i], bb[j], pa[i][j]);
  }
  float* pp = pgb + ((size_t)b * 8 + dt) * 4096;
#pragma unroll
  for (int i = 0; i < 4; ++i) {
    float4 v = make_float4(pa[i][0], pa[i][1], pa[i][2], pa[i][3]);
    *(float4*)(pp + (ty * 4 + i) * 64 + tx * 4) = v;
  }
}

// ---------------------------------------------------------------------------
// out[d][n] = sum_r B[d][r]*coef[n][r]
__global__ __launch_bounds__(256) void out_kernel(
    const float* __restrict__ bases, const float* __restrict__ coef,
    float* __restrict__ out) {
  __shared__ float bt[64 * 65];
  __shared__ float ct[64 * 65];
  const int nt = blockIdx.x, dt = blockIdx.y, b = blockIdx.z;
  const float* bp = bases + (size_t)b * DD * RR + (size_t)(dt * 64) * RR;
  const float* cp = coef + (size_t)b * NNPIX * RR + (size_t)(nt * 64) * RR;
  const int tid = threadIdx.x, tx = tid & 15, ty = tid >> 4;
  for (int idx = tid; idx < 1024; idx += 256) {
    const int row = idx >> 4, c4 = (idx & 15) * 4;
    const float4 v = *(const float4*)(bp + row * RR + c4);
    bt[row * 65 + c4 + 0] = v.x;
    bt[row * 65 + c4 + 1] = v.y;
    bt[row * 65 + c4 + 2] = v.z;
    bt[row * 65 + c4 + 3] = v.w;
    const float4 w = *(const float4*)(cp + row * RR + c4);
    ct[row * 65 + c4 + 0] = w.x;
    ct[row * 65 + c4 + 1] = w.y;
    ct[row * 65 + c4 + 2] = w.z;
    ct[row * 65 + c4 + 3] = w.w;
  }
  __syncthreads();
  float acc[4][4] = {};
#pragma unroll 4
  for (int r = 0; r < 64; ++r) {
    float a[4], bb[4];
#pragma unroll
    for (int i = 0; i < 4; ++i) a[i] = bt[(ty * 4 + i) * 65 + r];
#pragma unroll
    for (int j = 0; j < 4; ++j) bb[j] = ct[(tx * 4 + j) * 65 + r];
#pragma unroll
    for (int i = 0; i < 4; ++i)
#pragma unroll
      for (int j = 0; j < 4; ++j) acc[i][j] = fmaf(a[i], bb[j], acc[i][j]);
  }
  float* op = out + (size_t)b * DD * NNPIX + (size_t)(dt * 64) * NNPIX + nt * 64;
#pragma unroll
  for (int i = 0; i < 4; ++i) {
    float4 v = make_float4(acc[i][0], acc[i][1], acc[i][2], acc[i][3]);
    *(float4*)(op + (size_t)(ty * 4 + i) * NNPIX + tx * 4) = v;
  }
}

// ---------------------------------------------------------------------------
extern "C" void kernel_launch(void* const* d_in, const int* in_sizes, int n_in,
                              void* d_out, int out_size, void* d_ws,
                              size_t ws_size, hipStream_t stream) {
  (void)in_sizes; (void)n_in; (void)out_size; (void)ws_size;
  const float* x = (const float*)d_in[0];
  const float* bases_in = (const float*)d_in[1];

  float* W = (float*)d_ws;
  float* coef   = W;                       // 8*4096*64        = 2,097,152 f
  float* bases  = W + 2097152;             // 8*512*64         =   262,144 f
  float* gram_b = W + 2097152 + 262144;    // 8*64*64          =    32,768 f
  float* gram_c = gram_b + 32768;          //                  =    32,768 f

  float* O = (float*)d_out;                // 16,777,216 f total; scratch in front
  float* pgc = O;                          // 8*64*4096 = 2,097,152 f
  float* pgb = O + 2097152;                // 8*8*4096  =   262,144 f
  float* pnb = O + 2097152 + 262144;       // 8*4*512*64 = 1,048,576 f

  hipMemcpyAsync(bases, bases_in, (size_t)BATCH * DD * RR * sizeof(float),
                 hipMemcpyDeviceToDevice, stream);

  // gram_b of initial bases
  pgram_kernel<<<dim3(8, BATCH), 256, 0, stream>>>(bases, pgb, DD);
  greduce_kernel<<<128, 256, 0, stream>>>(pgb, gram_b, 8);

  // initial coef = softmax(INV_T * x^T bases)
  coef_kernel<0><<<dim3(64, BATCH), 256, 0, stream>>>(x, bases, nullptr, coef, nullptr);

  for (int step = 0; step < NSTEPS; ++step) {
    coef_kernel<1><<<dim3(64, BATCH), 256, 0, stream>>>(x, bases, gram_b, coef, pgc);
    greduce_kernel<<<128, 256, 0, stream>>>(pgc, gram_c, 64);
    numb_partial_kernel<<<dim3(4, 8, BATCH), 256, 0, stream>>>(x, coef, pnb);
    bases_update_kernel<<<dim3(8, BATCH), 256, 0, stream>>>(pnb, gram_c, bases, pgb);
    greduce_kernel<<<128, 256, 0, stream>>>(pgb, gram_b, 8);
  }

  // final coef update
  coef_kernel<2><<<dim3(64, BATCH), 256, 0, stream>>>(x, bases, gram_b, coef, nullptr);

  // reconstruction (writes ALL of d_out, erasing the scratch regions)
  out_kernel<<<dim3(64, 8, BATCH), 256, 0, stream>>>(bases, coef, O);
}

// Round 3
// 638.233 us; speedup vs baseline: 1.7613x; 1.7613x over previous
//
#include <hip/hip_runtime.h>
#include <math.h>

#define BATCH 8
#define DD 512
#define NN 4096
#define RR 64
#define NSTEPS 7
#define INV_T 100.0f
#define EPSV 1e-6f

typedef __attribute__((ext_vector_type(8))) _Float16 f16x8;
typedef __attribute__((ext_vector_type(4))) _Float16 f16x4;
typedef __attribute__((ext_vector_type(4))) float f32x4;

__device__ __forceinline__ _Float16 f2h(float f) { return (_Float16)f; }

// ---------------------------------------------------------------------------
// x fp32 [b][512][4096] -> x_h same layout + xT_h [b][4096][512]  (fp16)
__global__ __launch_bounds__(256) void xcvt_kernel(
    const float* __restrict__ x, _Float16* __restrict__ x_h,
    _Float16* __restrict__ xT_h) {
  __shared__ _Float16 t[64][72];
  const int n0 = blockIdx.x * 64, d0 = blockIdx.y * 64, b = blockIdx.z;
  const int tid = threadIdx.x;
  const size_t xbase = (size_t)(b * DD + d0) * NN + n0;
#pragma unroll
  for (int i = 0; i < 4; ++i) {
    const int idx = tid + i * 256;
    const int row = idx >> 4, c4 = (idx & 15) * 4;  // row=d, c4=n
    const float4 v = *(const float4*)(x + xbase + (size_t)row * NN + c4);
    f16x4 hv = {f2h(v.x), f2h(v.y), f2h(v.z), f2h(v.w)};
    *(f16x4*)(x_h + xbase + (size_t)row * NN + c4) = hv;
    *(f16x4*)&t[row][c4] = hv;
  }
  __syncthreads();
  const size_t tbase = (size_t)(b * NN + n0) * DD + d0;
#pragma unroll
  for (int i = 0; i < 4; ++i) {
    const int idx = tid + i * 256;
    const int row = idx >> 4, c4 = (idx & 15) * 4;  // row=n, c4=d
    f16x4 w = {t[c4][row], t[c4 + 1][row], t[c4 + 2][row], t[c4 + 3][row]};
    *(f16x4*)(xT_h + tbase + (size_t)row * DD + c4) = w;
  }
}

// ---------------------------------------------------------------------------
// bases_in fp32 [b][512][64] -> bases fp32 copy + bases_h + basesT_h [b][64][512]
__global__ __launch_bounds__(256) void bases_prep_kernel(
    const float* __restrict__ bin, float* __restrict__ bases,
    _Float16* __restrict__ bases_h, _Float16* __restrict__ basesT_h) {
  __shared__ float t[64][65];
  const int d0 = blockIdx.x * 64, b = blockIdx.y;
  const int tid = threadIdx.x;
  const size_t base = (size_t)(b * DD + d0) * RR;
#pragma unroll
  for (int i = 0; i < 4; ++i) {
    const int idx = tid + i * 256;
    const int row = idx >> 4, c4 = (idx & 15) * 4;  // row=d, c4=r
    const float4 v = *(const float4*)(bin + base + row * RR + c4);
    *(float4*)(bases + base + row * RR + c4) = v;
    f16x4 hv = {f2h(v.x), f2h(v.y), f2h(v.z), f2h(v.w)};
    *(f16x4*)(bases_h + base + row * RR + c4) = hv;
    t[row][c4] = v.x; t[row][c4 + 1] = v.y; t[row][c4 + 2] = v.z; t[row][c4 + 3] = v.w;
  }
  __syncthreads();
#pragma unroll
  for (int i = 0; i < 4; ++i) {
    const int idx = tid + i * 256;
    const int row = idx >> 4, c4 = (idx & 15) * 4;  // row=r, c4=d
    f16x4 w = {f2h(t[c4][row]), f2h(t[c4 + 1][row]), f2h(t[c4 + 2][row]),
               f2h(t[c4 + 3][row])};
    *(f16x4*)(basesT_h + (size_t)(b * RR + row) * DD + d0 + c4) = w;
  }
}

// ---------------------------------------------------------------------------
// partial gram of T [b][64][K] (k-contiguous): pg[b][split][64][64] fp32
__global__ __launch_bounds__(256) void gramT_kernel(
    const _Float16* __restrict__ T, float* __restrict__ pg, int K, int ksl) {
  const int sp = blockIdx.x, b = blockIdx.y;
  const int tid = threadIdx.x;
  const int w = tid >> 6, l = tid & 63, lo = l & 15, hi = l >> 4;
  const int k0 = sp * ksl;
  const _Float16* ap = T + (size_t)(b * RR + w * 16 + lo) * K + k0 + hi * 8;
  const _Float16* bp = T + (size_t)(b * RR + lo) * K + k0 + hi * 8;
  f32x4 acc[4] = {};
  for (int ks = 0; ks < ksl; ks += 32) {
    f16x8 a = *(const f16x8*)(ap + ks);
#pragma unroll
    for (int c = 0; c < 4; ++c) {
      f16x8 bb = *(const f16x8*)(bp + (size_t)c * 16 * K + ks);
      acc[c] = __builtin_amdgcn_mfma_f32_16x16x32_f16(a, bb, acc[c], 0, 0, 0);
    }
  }
  float* op = pg + ((size_t)(b * gridDim.x + sp) * RR + w * 16 + hi * 4) * RR;
#pragma unroll
  for (int c = 0; c < 4; ++c)
#pragma unroll
    for (int r = 0; r < 4; ++r) op[r * RR + c * 16 + lo] = acc[c][r];
}

// reduce splits -> gram fp32 + fp16
__global__ __launch_bounds__(256) void greduce2_kernel(
    const float* __restrict__ pg, int S, float* __restrict__ g32,
    _Float16* __restrict__ ghf) {
  const int idx = blockIdx.x * 256 + threadIdx.x;  // 0..32767
  const int b = idx >> 12, e = idx & 4095;
  const float* p = pg + (size_t)(b * S) * 4096 + e;
  float s = 0.f;
  for (int c = 0; c < S; ++c) s += p[(size_t)c * 4096];
  g32[idx] = s;
  ghf[idx] = f2h(s);
}

// ---------------------------------------------------------------------------
// coef update: num = x^T bases (MFMA, K=512). MODE 0: softmax init.
// MODE 1: coef = coef_old * num / (coef_old @ gram_b + eps)
template <int MODE>
__global__ __launch_bounds__(256) void coef_update_kernel(
    const _Float16* __restrict__ xT_h, const _Float16* __restrict__ basesT_h,
    const _Float16* __restrict__ gram_b_h, float* __restrict__ coef,
    _Float16* __restrict__ coef_h, _Float16* __restrict__ coefT_h) {
  const int nt = blockIdx.x, b = blockIdx.y;
  const int tid = threadIdx.x;
  const int w = tid >> 6, l = tid & 63, lo = l & 15, hi = l >> 4;
  const int n0 = nt * 64;

  const _Float16* ap = xT_h + (size_t)(b * NN + n0 + w * 16 + lo) * DD + hi * 8;
  const _Float16* bp = basesT_h + (size_t)(b * RR + lo) * DD + hi * 8;
  f32x4 acc[4] = {};
#pragma unroll
  for (int ks = 0; ks < 16; ++ks) {
    f16x8 a = *(const f16x8*)(ap + ks * 32);
#pragma unroll
    for (int c = 0; c < 4; ++c) {
      f16x8 bb = *(const f16x8*)(bp + (size_t)c * 16 * DD + ks * 32);
      acc[c] = __builtin_amdgcn_mfma_f32_16x16x32_f16(a, bb, acc[c], 0, 0, 0);
    }
  }

  float v[4][4];  // [c][reg]
  float* cp = coef + (size_t)(b * NN + n0 + w * 16 + hi * 4) * RR;

  if (MODE == 0) {
#pragma unroll
    for (int reg = 0; reg < 4; ++reg) {
      float m = fmaxf(fmaxf(acc[0][reg], acc[1][reg]),
                      fmaxf(acc[2][reg], acc[3][reg]));
      m = fmaxf(m, __shfl_xor(m, 1));
      m = fmaxf(m, __shfl_xor(m, 2));
      m = fmaxf(m, __shfl_xor(m, 4));
      m = fmaxf(m, __shfl_xor(m, 8));
      float s = 0.f, e[4];
#pragma unroll
      for (int c = 0; c < 4; ++c) {
        e[c] = expf(INV_T * (acc[c][reg] - m));
        s += e[c];
      }
      s += __shfl_xor(s, 1);
      s += __shfl_xor(s, 2);
      s += __shfl_xor(s, 4);
      s += __shfl_xor(s, 8);
      const float inv = 1.f / s;
#pragma unroll
      for (int c = 0; c < 4; ++c) v[c][reg] = e[c] * inv;
    }
  } else {
    // den = coef_old @ gram_b  (coef_h holds old coef, [n][r] fp16)
    const _Float16* dap = coef_h + (size_t)(b * NN + n0 + w * 16 + lo) * RR + hi * 8;
    f32x4 den[4] = {};
#pragma unroll
    for (int kk = 0; kk < 2; ++kk) {
      f16x8 a = *(const f16x8*)(dap + kk * 32);
#pragma unroll
      for (int c = 0; c < 4; ++c) {
        f16x8 g = *(const f16x8*)(gram_b_h + (size_t)(b * RR + c * 16 + lo) * RR +
                                  kk * 32 + hi * 8);
        den[c] = __builtin_amdgcn_mfma_f32_16x16x32_f16(a, g, den[c], 0, 0, 0);
      }
    }
#pragma unroll
    for (int reg = 0; reg < 4; ++reg)
#pragma unroll
      for (int c = 0; c < 4; ++c) {
        const float oldc = cp[reg * RR + c * 16 + lo];
        v[c][reg] = oldc * acc[c][reg] / (den[c][reg] + EPSV);
      }
  }

  // stores: fp32 master, coef_h [n][r], coefT_h [r][n]
#pragma unroll
  for (int reg = 0; reg < 4; ++reg)
#pragma unroll
    for (int c = 0; c < 4; ++c) {
      cp[reg * RR + c * 16 + lo] = v[c][reg];
      coef_h[(size_t)(b * NN + n0 + w * 16 + hi * 4 + reg) * RR + c * 16 + lo] =
          f2h(v[c][reg]);
    }
#pragma unroll
  for (int c = 0; c < 4; ++c) {
    f16x4 t4 = {f2h(v[c][0]), f2h(v[c][1]), f2h(v[c][2]), f2h(v[c][3])};
    *(f16x4*)(coefT_h + (size_t)(b * RR + c * 16 + lo) * NN + n0 + w * 16 + hi * 4) = t4;
  }
}

// ---------------------------------------------------------------------------
// num_b partials: pnb[b][kc][512][64] = x_h[d][kslice] @ coefT_h[r][kslice]^T
__global__ __launch_bounds__(256) void numb_kernel(
    const _Float16* __restrict__ x_h, const _Float16* __restrict__ coefT_h,
    float* __restrict__ pnb) {
  const int kc = blockIdx.x, dt = blockIdx.y, b = blockIdx.z;
  const int tid = threadIdx.x;
  const int w = tid >> 6, l = tid & 63, lo = l & 15, hi = l >> 4;
  const _Float16* ap =
      x_h + (size_t)(b * DD + dt * 64 + w * 16 + lo) * NN + kc * 1024 + hi * 8;
  const _Float16* bp = coefT_h + (size_t)(b * RR + lo) * NN + kc * 1024 + hi * 8;
  f32x4 acc[4] = {};
#pragma unroll 4
  for (int ks = 0; ks < 32; ++ks) {
    f16x8 a = *(const f16x8*)(ap + ks * 32);
#pragma unroll
    for (int c = 0; c < 4; ++c) {
      f16x8 bb = *(const f16x8*)(bp + (size_t)c * 16 * NN + ks * 32);
      acc[c] = __builtin_amdgcn_mfma_f32_16x16x32_f16(a, bb, acc[c], 0, 0, 0);
    }
  }
  float* op = pnb + ((size_t)((b * 4 + kc) * DD) + dt * 64 + w * 16 + hi * 4) * RR;
#pragma unroll
  for (int c = 0; c < 4; ++c)
#pragma unroll
    for (int r = 0; r < 4; ++r) op[r * RR + c * 16 + lo] = acc[c][r];
}

// ---------------------------------------------------------------------------
// bases update (fp32): B *= num_b/(B@gram_c+eps); writes fp32 + fp16 + fp16^T
__global__ __launch_bounds__(256) void bases_update_kernel(
    const float* __restrict__ pnb, const float* __restrict__ gram_c,
    float* __restrict__ bases, _Float16* __restrict__ bases_h,
    _Float16* __restrict__ basesT_h) {
  __shared__ float bsm[64 * 65];
  __shared__ float gs[64 * 64];
  const int dt = blockIdx.x, b = blockIdx.y;
  float* bg = bases + (size_t)(b * DD + dt * 64) * RR;
  const int tid = threadIdx.x, tx = tid & 15, ty = tid >> 4;
  for (int idx = tid; idx < 4096; idx += 256) {
    const int row = idx >> 6, cc = idx & 63;
    bsm[row * 65 + cc] = bg[row * 64 + cc];
  }
  const float* gcp = gram_c + (size_t)b * 4096;
  for (int idx = tid; idx < 1024; idx += 256)
    *(float4*)&gs[idx * 4] = *(const float4*)(gcp + idx * 4);
  __syncthreads();

  float nb[4][4];
#pragma unroll
  for (int i = 0; i < 4; ++i) {
    float4 s = make_float4(0.f, 0.f, 0.f, 0.f);
#pragma unroll
    for (int kc = 0; kc < 4; ++kc) {
      const float4 vv = *(const float4*)(pnb +
          (((size_t)b * 4 + kc) * DD + dt * 64 + ty * 4 + i) * RR + tx * 4);
      s.x += vv.x; s.y += vv.y; s.z += vv.z; s.w += vv.w;
    }
    nb[i][0] = s.x; nb[i][1] = s.y; nb[i][2] = s.z; nb[i][3] = s.w;
  }

  float den[4][4] = {};
  for (int s = 0; s < 64; ++s) {
    float a[4];
#pragma unroll
    for (int i = 0; i < 4; ++i) a[i] = bsm[(ty * 4 + i) * 65 + s];
    const float4 gv = *(float4*)&gs[s * 64 + tx * 4];
    const float g4[4] = {gv.x, gv.y, gv.z, gv.w};
#pragma unroll
    for (int i = 0; i < 4; ++i)
#pragma unroll
      for (int j = 0; j < 4; ++j) den[i][j] = fmaf(a[i], g4[j], den[i][j]);
  }

  float v[4][4];
#pragma unroll
  for (int i = 0; i < 4; ++i) {
    float4 vv;
#pragma unroll
    for (int j = 0; j < 4; ++j) {
      const float oldb = bsm[(ty * 4 + i) * 65 + tx * 4 + j];
      v[i][j] = oldb * nb[i][j] / (den[i][j] + EPSV);
    }
    vv.x = v[i][0]; vv.y = v[i][1]; vv.z = v[i][2]; vv.w = v[i][3];
    *(float4*)&bg[(ty * 4 + i) * 64 + tx * 4] = vv;
    f16x4 bv = {f2h(v[i][0]), f2h(v[i][1]), f2h(v[i][2]), f2h(v[i][3])};
    *(f16x4*)(bases_h + (size_t)(b * DD + dt * 64 + ty * 4 + i) * RR + tx * 4) = bv;
  }
#pragma unroll
  for (int j = 0; j < 4; ++j) {
    f16x4 tv = {f2h(v[0][j]), f2h(v[1][j]), f2h(v[2][j]), f2h(v[3][j])};
    *(f16x4*)(basesT_h + (size_t)(b * RR + tx * 4 + j) * DD + dt * 64 + ty * 4) = tv;
  }
}

// ---------------------------------------------------------------------------
// out[d][n] = sum_r bases_h[d][r] * coef_h[n][r]  (MFMA, K=64)
__global__ __launch_bounds__(256) void out_kernel(
    const _Float16* __restrict__ bases_h, const _Float16* __restrict__ coef_h,
    float* __restrict__ out) {
  const int nt = blockIdx.x, dt = blockIdx.y, b = blockIdx.z;
  const int tid = threadIdx.x;
  const int w = tid >> 6, l = tid & 63, lo = l & 15, hi = l >> 4;
  const int n0 = nt * 64;
  const _Float16* ap =
      bases_h + (size_t)(b * DD + dt * 64 + w * 16 + lo) * RR + hi * 8;
  f32x4 acc[4] = {};
#pragma unroll
  for (int kk = 0; kk < 2; ++kk) {
    f16x8 a = *(const f16x8*)(ap + kk * 32);
#pragma unroll
    for (int c = 0; c < 4; ++c) {
      f16x8 bb = *(const f16x8*)(coef_h + (size_t)(b * NN + n0 + c * 16 + lo) * RR +
                                 kk * 32 + hi * 8);
      acc[c] = __builtin_amdgcn_mfma_f32_16x16x32_f16(a, bb, acc[c], 0, 0, 0);
    }
  }
  float* op = out + (size_t)(b * DD + dt * 64 + w * 16 + hi * 4) * NN + n0;
#pragma unroll
  for (int c = 0; c < 4; ++c)
#pragma unroll
    for (int r = 0; r < 4; ++r) op[(size_t)r * NN + c * 16 + lo] = acc[c][r];
}

// ---------------------------------------------------------------------------
extern "C" void kernel_launch(void* const* d_in, const int* in_sizes, int n_in,
                              void* d_out, int out_size, void* d_ws,
                              size_t ws_size, hipStream_t stream) {
  (void)in_sizes; (void)n_in; (void)out_size; (void)ws_size;
  const float* x = (const float*)d_in[0];
  const float* bases_in = (const float*)d_in[1];

  // fp32 workspace
  float* W = (float*)d_ws;
  size_t o = 0;
  float* coef = W + o;     o += (size_t)BATCH * NN * RR;   // 2,097,152
  float* bases = W + o;    o += (size_t)BATCH * DD * RR;   //   262,144
  float* gram_b32 = W + o; o += (size_t)BATCH * 4096;      //    32,768
  float* gram_c32 = W + o; o += (size_t)BATCH * 4096;      //    32,768
  float* pnb = W + o;      o += (size_t)BATCH * 4 * DD * RR;  // 1,048,576
  float* pgram = W + o;    o += (size_t)BATCH * 16 * 4096;    //   524,288
  // fp16 workspace
  _Float16* U = (_Float16*)(W + o);
  size_t u = 0;
  _Float16* coef_h = U + u;   u += (size_t)BATCH * NN * RR;
  _Float16* coefT_h = U + u;  u += (size_t)BATCH * NN * RR;
  _Float16* bases_h = U + u;  u += (size_t)BATCH * DD * RR;
  _Float16* basesT_h = U + u; u += (size_t)BATCH * DD * RR;
  _Float16* gram_b_h = U + u; u += (size_t)BATCH * 4096;
  _Float16* gram_c_h = U + u; u += (size_t)BATCH * 4096;

  // x fp16 copies live in d_out (exactly fills it; overwritten by out_kernel last)
  _Float16* xT_h = (_Float16*)d_out;          // [b][4096][512]
  _Float16* x_h = xT_h + (size_t)BATCH * NN * DD;  // [b][512][4096]

  xcvt_kernel<<<dim3(64, 8, BATCH), 256, 0, stream>>>(x, x_h, xT_h);
  bases_prep_kernel<<<dim3(8, BATCH), 256, 0, stream>>>(bases_in, bases, bases_h,
                                                        basesT_h);
  gramT_kernel<<<dim3(4, BATCH), 256, 0, stream>>>(basesT_h, pgram, DD, 128);
  greduce2_kernel<<<128, 256, 0, stream>>>(pgram, 4, gram_b32, gram_b_h);

  coef_update_kernel<0><<<dim3(64, BATCH), 256, 0, stream>>>(
      xT_h, basesT_h, gram_b_h, coef, coef_h, coefT_h);

  for (int step = 0; step < NSTEPS; ++step) {
    coef_update_kernel<1><<<dim3(64, BATCH), 256, 0, stream>>>(
        xT_h, basesT_h, gram_b_h, coef, coef_h, coefT_h);
    gramT_kernel<<<dim3(16, BATCH), 256, 0, stream>>>(coefT_h, pgram, NN, 256);
    greduce2_kernel<<<128, 256, 0, stream>>>(pgram, 16, gram_c32, gram_c_h);
    numb_kernel<<<dim3(4, 8, BATCH), 256, 0, stream>>>(x_h, coefT_h, pnb);
    bases_update_kernel<<<dim3(8, BATCH), 256, 0, stream>>>(pnb, gram_c32, bases,
                                                            bases_h, basesT_h);
    gramT_kernel<<<dim3(4, BATCH), 256, 0, stream>>>(basesT_h, pgram, DD, 128);
    greduce2_kernel<<<128, 256, 0, stream>>>(pgram, 4, gram_b32, gram_b_h);
  }

  // final coef update
  coef_update_kernel<1><<<dim3(64, BATCH), 256, 0, stream>>>(
      xT_h, basesT_h, gram_b_h, coef, coef_h, coefT_h);

  // reconstruction (overwrites all of d_out)
  out_kernel<<<dim3(64, 8, BATCH), 256, 0, stream>>>(bases_h, coef_h, (float*)d_out);
}